// Round 1
// baseline (251.403 us; speedup 1.0000x reference)
//
#include <hip/hip_runtime.h>
#include <stdint.h>

#define D 128
#define K_NEI 10
#define TILE_M 64   // fused-fallback tile

typedef __bf16 bf16x8 __attribute__((ext_vector_type(8)));
typedef float f32x4 __attribute__((ext_vector_type(4)));

__device__ __forceinline__ uint32_t f2bf(float f) {
    union { float f; uint32_t u; } v; v.f = f;
    uint32_t u = v.u;
    return (u + 0x7FFFu + ((u >> 16) & 1u)) >> 16;   // RNE
}
__device__ __forceinline__ float bf2f(uint32_t h) {
    union { uint32_t u; float f; } v; v.u = h << 16; return v.f;
}
__device__ __forceinline__ uint32_t pack2(float a, float b) {
    return f2bf(a) | (f2bf(b) << 16);
}
__device__ __forceinline__ bf16x8 u4_as_bf16x8(uint4 u) {
    union { uint4 u; bf16x8 b; } v; v.u = u; return v.b;
}

// HW bf16 conversion (compiler emits v_cvt_pk_bf16_f32 for pairs)
__device__ __forceinline__ uint2 cvt4(f32x4 v) {
    union { __bf16 b[4]; uint2 u; } o;
    o.b[0] = (__bf16)v[0]; o.b[1] = (__bf16)v[1];
    o.b[2] = (__bf16)v[2]; o.b[3] = (__bf16)v[3];
    return o.u;
}
__device__ __forceinline__ bf16x8 cvt8(f32x4 lo, f32x4 hi) {
    union { __bf16 b[8]; bf16x8 v; } o;
    o.b[0] = (__bf16)lo[0]; o.b[1] = (__bf16)lo[1];
    o.b[2] = (__bf16)lo[2]; o.b[3] = (__bf16)lo[3];
    o.b[4] = (__bf16)hi[0]; o.b[5] = (__bf16)hi[1];
    o.b[6] = (__bf16)hi[2]; o.b[7] = (__bf16)hi[3];
    return o.v;
}

// ============================================================================
// convert_W2: W1,W2 [128][256] fp32 -> W1b,W2b [256][128] bf16
// Wb[c][k] = W[c & 127][(c>>7)*128 + k]. 32 blocks: 0..15 -> W1, 16..31 -> W2.
// ============================================================================
__global__ void convert_W2(const float* __restrict__ Wa, const float* __restrict__ Wb_in,
                           uint16_t* __restrict__ Oa, uint16_t* __restrict__ Ob)
{
    const float* W = (blockIdx.x < 16) ? Wa : Wb_in;
    uint16_t*    O = (blockIdx.x < 16) ? Oa : Ob;
    int t = (blockIdx.x & 15) * 256 + threadIdx.x;   // 0..4095
    int c = t >> 4, j = t & 15;
    const float* src = W + (size_t)(c & 127) * 256 + (c >> 7) * 128 + j * 8;
    f32x4 a = *(const f32x4*)src;
    f32x4 b = *(const f32x4*)(src + 4);
    uint4 o;
    o.x = pack2(a[0], a[1]); o.y = pack2(a[2], a[3]);
    o.z = pack2(b[0], b[1]); o.w = pack2(b[2], b[3]);
    *(uint4*)(O + (size_t)c * 128 + j * 8) = o;
}

// ============================================================================
// gemm_rw: P[M][256] = A[M][128] @ Wb^T  (bf16 out, no relu)
// W-stationary IN REGISTERS: each wave holds one 128-col half of Wb as
// 8x4 MFMA A-fragments (128 VGPR). No LDS, no barriers, no ds_reads.
// Operands SWAPPED vs the classic layout: mfma(Wfrag, Afrag, acc) gives
//   D row  = W-col  = q*4 + reg   (4 CONSECUTIVE cols per lane)
//   D col  = node   = lane & 15
// so the epilogue is 8x 8-byte dwordx2 stores per tile (was 64x 2-byte).
// Grid-stride over 16-row tiles; 2 waves (col-halves) per tile.
// ============================================================================
template <bool A_F32>
__global__ __launch_bounds__(256, 2)
void gemm_rw(const void* __restrict__ Asrc_,
             const uint16_t* __restrict__ Wb,
             uint16_t* __restrict__ P, int M)
{
    const int tid  = threadIdx.x;
    const int wave = tid >> 6;
    const int lane = tid & 63;
    const int r16  = lane & 15;
    const int q    = lane >> 4;
    const int h    = wave & 1;                       // which 128-col half

    const int nTiles = M >> 4;
    const int stride = gridDim.x * 2;                // 2 waves per tile
    int tile = blockIdx.x * 2 + (wave >> 1);
    if (tile >= nTiles) return;

    // ---- W half resident in registers: frag[nt][ks] = Wb[h*128+nt*16+r16][ks*32+q*8 ..+7]
    bf16x8 Bf[8][4];
    {
        const uint16_t* wb = Wb + (size_t)(h * 128 + r16) * 128 + q * 8;
        #pragma unroll
        for (int nt = 0; nt < 8; ++nt)
            #pragma unroll
            for (int ks = 0; ks < 4; ++ks)
                Bf[nt][ks] = *(const bf16x8*)(wb + nt * 16 * 128 + ks * 32);
    }

    // raw prefetch buffers (convert deferred to use so vmcnt waits can sink)
    f32x4 preF[8];  uint4 preB[4];

    if (A_F32) {
        const float* row = (const float*)Asrc_ + (size_t)(tile * 16 + r16) * D + q * 8;
        #pragma unroll
        for (int ks = 0; ks < 4; ++ks) {
            preF[2 * ks]     = *(const f32x4*)(row + ks * 32);
            preF[2 * ks + 1] = *(const f32x4*)(row + ks * 32 + 4);
        }
    } else {
        const uint16_t* row = (const uint16_t*)Asrc_ + (size_t)(tile * 16 + r16) * D + q * 8;
        #pragma unroll
        for (int ks = 0; ks < 4; ++ks)
            preB[ks] = *(const uint4*)(row + ks * 32);
    }

    while (tile < nTiles) {
        const int nxt = tile + stride;

        // ---- build current node fragments (B-operand) from prefetch buffers
        bf16x8 a[4];
        if (A_F32) {
            #pragma unroll
            for (int ks = 0; ks < 4; ++ks)
                a[ks] = cvt8(preF[2 * ks], preF[2 * ks + 1]);
        } else {
            #pragma unroll
            for (int ks = 0; ks < 4; ++ks) a[ks] = u4_as_bf16x8(preB[ks]);
        }

        // ---- prefetch next tile (loads in flight across the MFMA block)
        if (nxt < nTiles) {
            if (A_F32) {
                const float* row = (const float*)Asrc_ + (size_t)(nxt * 16 + r16) * D + q * 8;
                #pragma unroll
                for (int ks = 0; ks < 4; ++ks) {
                    preF[2 * ks]     = *(const f32x4*)(row + ks * 32);
                    preF[2 * ks + 1] = *(const f32x4*)(row + ks * 32 + 4);
                }
            } else {
                const uint16_t* row = (const uint16_t*)Asrc_ + (size_t)(nxt * 16 + r16) * D + q * 8;
                #pragma unroll
                for (int ks = 0; ks < 4; ++ks)
                    preB[ks] = *(const uint4*)(row + ks * 32);
            }
        }

        // ---- compute: 32 MFMA, W as A-operand (swapped)
        f32x4 acc[8];
        #pragma unroll
        for (int nt = 0; nt < 8; ++nt) acc[nt] = (f32x4){0.f, 0.f, 0.f, 0.f};

        #pragma unroll
        for (int ks = 0; ks < 4; ++ks)
            #pragma unroll
            for (int nt = 0; nt < 8; ++nt)
                acc[nt] = __builtin_amdgcn_mfma_f32_16x16x32_bf16(Bf[nt][ks], a[ks], acc[nt], 0, 0, 0);

        // ---- store: lane owns row tile*16+r16, cols h*128 + nt*16 + q*4 .. +3
        uint16_t* dst = P + (size_t)(tile * 16 + r16) * 256 + h * 128 + q * 4;
        #pragma unroll
        for (int nt = 0; nt < 8; ++nt)
            *(uint2*)(dst + nt * 16) = cvt4(acc[nt]);

        tile = nxt;
    }
}

// ============================================================================
// combine: out[i] = relu(Pl[self_idx[i]] + 0.1 * sum_k Pr[neigh[i][k]])
// P rows [256] bf16 (Pl=0..127, Pr=128..255). 16 thr/node, 16 B gathers.
// ============================================================================
template <bool OUT_F32>
__global__ void combine(const uint16_t* __restrict__ P,
                        const int* __restrict__ self_idx,
                        const int* __restrict__ neigh_idx,
                        void* __restrict__ out_, int M)
{
    const int t = blockIdx.x * 256 + threadIdx.x;
    const int i = t >> 4;
    const int j = t & 15;
    if (i >= M) return;

    uint4 sv = *(const uint4*)(P + (size_t)self_idx[i] * 256 + j * 8);

    // 10 indices via 5 x int2 (rows are 40 B, 8 B aligned)
    const int2* nrow2 = (const int2*)(neigh_idx + (size_t)i * K_NEI);
    int idx[K_NEI];
    #pragma unroll
    for (int k = 0; k < 5; ++k) {
        int2 p = nrow2[k];
        idx[2 * k] = p.x; idx[2 * k + 1] = p.y;
    }

    float s0=0,s1=0,s2=0,s3=0,s4=0,s5=0,s6=0,s7=0;
    #pragma unroll
    for (int k = 0; k < K_NEI; ++k) {
        uint4 v = *(const uint4*)(P + (size_t)idx[k] * 256 + 128 + j * 8);
        s0 += bf2f(v.x & 0xFFFFu); s1 += bf2f(v.x >> 16);
        s2 += bf2f(v.y & 0xFFFFu); s3 += bf2f(v.y >> 16);
        s4 += bf2f(v.z & 0xFFFFu); s5 += bf2f(v.z >> 16);
        s6 += bf2f(v.w & 0xFFFFu); s7 += bf2f(v.w >> 16);
    }
    const float inv = 0.1f;
    float r0 = bf2f(sv.x & 0xFFFFu) + s0 * inv, r1 = bf2f(sv.x >> 16) + s1 * inv;
    float r2 = bf2f(sv.y & 0xFFFFu) + s2 * inv, r3 = bf2f(sv.y >> 16) + s3 * inv;
    float r4 = bf2f(sv.z & 0xFFFFu) + s4 * inv, r5 = bf2f(sv.z >> 16) + s5 * inv;
    float r6 = bf2f(sv.w & 0xFFFFu) + s6 * inv, r7 = bf2f(sv.w >> 16) + s7 * inv;
    r0 = r0 > 0.f ? r0 : 0.f; r1 = r1 > 0.f ? r1 : 0.f;
    r2 = r2 > 0.f ? r2 : 0.f; r3 = r3 > 0.f ? r3 : 0.f;
    r4 = r4 > 0.f ? r4 : 0.f; r5 = r5 > 0.f ? r5 : 0.f;
    r6 = r6 > 0.f ? r6 : 0.f; r7 = r7 > 0.f ? r7 : 0.f;

    if (OUT_F32) {
        float* dst = (float*)out_ + (size_t)i * D + j * 8;
        *(f32x4*)dst       = (f32x4){r0, r1, r2, r3};
        *(f32x4*)(dst + 4) = (f32x4){r4, r5, r6, r7};
    } else {
        uint4 o;
        o.x = pack2(r0, r1); o.y = pack2(r2, r3);
        o.z = pack2(r4, r5); o.w = pack2(r6, r7);
        *(uint4*)((uint16_t*)out_ + (size_t)i * D + j * 8) = o;
    }
}

// ============================================================================
// Fallback: R3 fused kernel (proven) — only if ws too small for path A.
// ============================================================================
template <bool FEATS_F32, bool OUT_F32>
__global__ void sage_layer(const void* __restrict__ feats_,
                           const float* __restrict__ W,
                           const int* __restrict__ self_idx,
                           const int* __restrict__ neigh_idx,
                           void* __restrict__ out_)
{
    __shared__ __align__(16) uint16_t Alds[TILE_M * 128];
    __shared__ __align__(16) uint16_t Wlds[128 * 128];

    const int tid  = threadIdx.x;
    const int wave = tid >> 6;
    const int lane = tid & 63;
    const int r16  = lane & 15;
    const int q    = lane >> 4;
    const int G    = blockIdx.x * TILE_M;

    const float*    feats_f = (const float*)feats_;
    const uint16_t* feats_b = (const uint16_t*)feats_;

    f32x4 acc[8];
    #pragma unroll
    for (int nt = 0; nt < 8; ++nt) acc[nt] = (f32x4){0.f, 0.f, 0.f, 0.f};

    for (int half = 0; half < 2; ++half) {
        #pragma unroll
        for (int it = 0; it < 8; ++it) {
            int t = it * 256 + tid;
            int j = t >> 4, c = t & 15;
            const float* src = W + (size_t)j * 256 + half * 128 + c * 8;
            f32x4 w0 = *(const f32x4*)(src);
            f32x4 w1 = *(const f32x4*)(src + 4);
            uint4 o;
            o.x = pack2(w0[0], w0[1]); o.y = pack2(w0[2], w0[3]);
            o.z = pack2(w1[0], w1[1]); o.w = pack2(w1[2], w1[3]);
            int cs = c ^ (j & 15);
            *(uint4*)(Wlds + j * 128 + cs * 8) = o;
        }
        if (half == 0) {
            #pragma unroll
            for (int it = 0; it < 4; ++it) {
                int t = it * 256 + tid;
                int n = t >> 4, c = t & 15;
                int node = self_idx[G + n];
                uint4 o;
                if (FEATS_F32) {
                    const float* src = feats_f + (size_t)node * D + c * 8;
                    f32x4 f0 = *(const f32x4*)(src);
                    f32x4 f1 = *(const f32x4*)(src + 4);
                    o.x = pack2(f0[0], f0[1]); o.y = pack2(f0[2], f0[3]);
                    o.z = pack2(f1[0], f1[1]); o.w = pack2(f1[2], f1[3]);
                } else {
                    o = *(const uint4*)(feats_b + (size_t)node * D + c * 8);
                }
                int cs = c ^ (n & 15);
                *(uint4*)(Alds + n * 128 + cs * 8) = o;
            }
        } else {
            #pragma unroll
            for (int it = 0; it < 4; ++it) {
                int t = it * 256 + tid;
                int n = t >> 4, c = t & 15;
                const int* nrow = neigh_idx + (size_t)(G + n) * K_NEI;
                float s0=0,s1=0,s2=0,s3=0,s4=0,s5=0,s6=0,s7=0;
                #pragma unroll
                for (int k = 0; k < K_NEI; ++k) {
                    if (FEATS_F32) {
                        const float* src = feats_f + (size_t)nrow[k] * D + c * 8;
                        f32x4 f0 = *(const f32x4*)(src);
                        f32x4 f1 = *(const f32x4*)(src + 4);
                        s0 += f0[0]; s1 += f0[1]; s2 += f0[2]; s3 += f0[3];
                        s4 += f1[0]; s5 += f1[1]; s6 += f1[2]; s7 += f1[3];
                    } else {
                        uint4 v = *(const uint4*)(feats_b + (size_t)nrow[k] * D + c * 8);
                        s0 += bf2f(v.x & 0xFFFFu); s1 += bf2f(v.x >> 16);
                        s2 += bf2f(v.y & 0xFFFFu); s3 += bf2f(v.y >> 16);
                        s4 += bf2f(v.z & 0xFFFFu); s5 += bf2f(v.z >> 16);
                        s6 += bf2f(v.w & 0xFFFFu); s7 += bf2f(v.w >> 16);
                    }
                }
                const float inv = 0.1f;
                uint4 o;
                o.x = pack2(s0 * inv, s1 * inv);
                o.y = pack2(s2 * inv, s3 * inv);
                o.z = pack2(s4 * inv, s5 * inv);
                o.w = pack2(s6 * inv, s7 * inv);
                int cs = c ^ (n & 15);
                *(uint4*)(Alds + n * 128 + cs * 8) = o;
            }
        }
        __syncthreads();

        #pragma unroll
        for (int ks = 0; ks < 4; ++ks) {
            int cidx = ks * 4 + q;
            bf16x8 a = *(const bf16x8*)(Alds + (wave * 16 + r16) * 128 + ((cidx ^ r16) * 8));
            bf16x8 b[8];
            #pragma unroll
            for (int nt = 0; nt < 8; ++nt) {
                int jj = nt * 16 + r16;
                b[nt] = *(const bf16x8*)(Wlds + jj * 128 + ((cidx ^ r16) * 8));
            }
            #pragma unroll
            for (int nt = 0; nt < 8; ++nt)
                acc[nt] = __builtin_amdgcn_mfma_f32_16x16x32_bf16(a, b[nt], acc[nt], 0, 0, 0);
        }
        __syncthreads();
    }

    const int row_base = G + wave * 16 + q * 4;
    #pragma unroll
    for (int nt = 0; nt < 8; ++nt) {
        int col = nt * 16 + r16;
        #pragma unroll
        for (int r = 0; r < 4; ++r) {
            float v = acc[nt][r];
            v = v > 0.f ? v : 0.f;
            if (OUT_F32) ((float*)out_)[(size_t)(row_base + r) * D + col] = v;
            else ((uint16_t*)out_)[(size_t)(row_base + r) * D + col] = (uint16_t)f2bf(v);
        }
    }
}

extern "C" void kernel_launch(void* const* d_in, const int* in_sizes, int n_in,
                              void* d_out, int out_size, void* d_ws, size_t ws_size,
                              hipStream_t stream) {
    const float* raw = (const float*)d_in[0];          // [200000][128] fp32
    const float* W1  = (const float*)d_in[1];          // [128][256] fp32
    const float* W2  = (const float*)d_in[2];          // [128][256] fp32
    const int* layer1_nodes = (const int*)d_in[3];     // [81920]
    const int* neigh0       = (const int*)d_in[4];     // [81920][10]
    const int* map_batch    = (const int*)d_in[5];     // [8192]
    const int* neigh1       = (const int*)d_in[6];     // [8192][10]

    const int N_NODES = in_sizes[0] / D;   // 200000
    const int N1 = in_sizes[3];            // 81920
    const int B  = in_sizes[5];            // 8192

    const size_t szP  = (size_t)N_NODES * 256 * 2;
    const size_t szQ  = (size_t)N1 * 256 * 2;
    const size_t szH1 = (size_t)N1 * 128 * 2;
    const size_t szW  = 256 * 128 * 2;
    const size_t needA = (szP > szQ ? szP : szQ) + szH1 + 2 * szW;

    if (ws_size >= needA && (N_NODES % 16) == 0 && (N1 % 16) == 0 && (B % 16) == 0) {
        uint16_t* Pbuf = (uint16_t*)d_ws;                       // P, later aliased by Q
        uint16_t* h1   = (uint16_t*)((char*)d_ws + (szP > szQ ? szP : szQ));
        uint16_t* W1b  = h1 + (size_t)N1 * 128;
        uint16_t* W2b  = W1b + 256 * 128;

        convert_W2<<<32, 256, 0, stream>>>(W1, W2, W1b, W2b);

        // 512 blocks = exactly 2 blocks/CU resident (VGPR-capped); each wave
        // grid-strides ~12 (layer1) / ~5 (layer2) tile-halves, amortizing the
        // one-time 32x16B register-W load.
        gemm_rw<true ><<<512, 256, 0, stream>>>(raw, W1b, Pbuf, N_NODES);

        combine<false><<<(N1 * 16 + 255) / 256, 256, 0, stream>>>(Pbuf, layer1_nodes, neigh0, h1, N1);

        gemm_rw<false><<<512, 256, 0, stream>>>(h1, W2b, Pbuf, N1);

        combine<true ><<<(B * 16 + 255) / 256, 256, 0, stream>>>(Pbuf, map_batch, neigh1, d_out, B);
        return;
    }

    // Fallback: R3 fused path
    uint16_t* h1 = (uint16_t*)d_ws;
    sage_layer<true,  false><<<N1 / TILE_M, 256, 0, stream>>>(raw, W1, layer1_nodes, neigh0, h1);
    sage_layer<false, true ><<<B  / TILE_M, 256, 0, stream>>>(h1,  W2, map_batch,    neigh1, d_out);
}

// Round 2
// 236.117 us; speedup vs baseline: 1.0647x; 1.0647x over previous
//
#include <hip/hip_runtime.h>
#include <stdint.h>

#define D 128
#define K_NEI 10
#define TILE_M 64   // fused-fallback tile

typedef __bf16 bf16x8 __attribute__((ext_vector_type(8)));
typedef float f32x4 __attribute__((ext_vector_type(4)));

__device__ __forceinline__ uint32_t f2bf(float f) {
    union { float f; uint32_t u; } v; v.f = f;
    uint32_t u = v.u;
    return (u + 0x7FFFu + ((u >> 16) & 1u)) >> 16;   // RNE
}
__device__ __forceinline__ float bf2f(uint32_t h) {
    union { uint32_t u; float f; } v; v.u = h << 16; return v.f;
}
__device__ __forceinline__ uint32_t pack2(float a, float b) {
    return f2bf(a) | (f2bf(b) << 16);
}
__device__ __forceinline__ bf16x8 u4_as_bf16x8(uint4 u) {
    union { uint4 u; bf16x8 b; } v; v.u = u; return v.b;
}
// HW bf16 conversion (compiler emits v_cvt_pk_bf16_f32 for pairs)
__device__ __forceinline__ uint2 cvt4(f32x4 v) {
    union { __bf16 b[4]; uint2 u; } o;
    o.b[0] = (__bf16)v[0]; o.b[1] = (__bf16)v[1];
    o.b[2] = (__bf16)v[2]; o.b[3] = (__bf16)v[3];
    return o.u;
}

// ============================================================================
// convert_Wc: W1,W2 [128][256] fp32 -> bf16 SAME layout (no transpose needed:
// with swapped-operand MFMA the A-operand m-index is the W output column and
// k runs over the 256-wide concat axis, both contiguous in the native layout).
// ============================================================================
__global__ void convert_Wc(const float* __restrict__ W1, const float* __restrict__ W2,
                           uint16_t* __restrict__ O1, uint16_t* __restrict__ O2)
{
    const float* W = (blockIdx.x < 16) ? W1 : W2;
    uint16_t*    O = (blockIdx.x < 16) ? O1 : O2;
    int t = (blockIdx.x & 15) * 256 + threadIdx.x;   // 0..4095, 8 elems each
    const float* src = W + (size_t)t * 8;
    f32x4 a = *(const f32x4*)src;
    f32x4 b = *(const f32x4*)(src + 4);
    uint4 o;
    o.x = cvt4(a).x; o.y = cvt4(a).y;
    o.z = cvt4(b).x; o.w = cvt4(b).y;
    *(uint4*)(O + (size_t)t * 8) = o;
}

// ============================================================================
// gather_agg: C[i] = [ src[self_idx[i]] | 0.1 * sum_k src[neigh_idx[i][k]] ]
// C rows are [256] bf16. Mean-before-matmul (commutes with the linear layer).
// 16 threads/node; fp32 accumulation; fully coalesced 128-256 B segments.
// ============================================================================
template <bool SRC_F32>
__global__ void gather_agg(const void* __restrict__ src_,
                           const int* __restrict__ self_idx,
                           const int* __restrict__ neigh_idx,
                           uint16_t* __restrict__ C, int M)
{
    const int t = blockIdx.x * 256 + threadIdx.x;
    const int i = t >> 4;        // node
    const int j = t & 15;        // lane-within-node
    if (i >= M) return;

    // 10 indices via 5 x int2 (rows are 40 B, 8 B aligned)
    const int2* nrow2 = (const int2*)(neigh_idx + (size_t)i * K_NEI);
    int idx[K_NEI];
    #pragma unroll
    for (int k = 0; k < 5; ++k) {
        int2 p = nrow2[k];
        idx[2 * k] = p.x; idx[2 * k + 1] = p.y;
    }
    const int self = self_idx[i];
    uint16_t* c = C + (size_t)i * 256;

    if (SRC_F32) {
        const float* src = (const float*)src_;
        // lane j covers cols [j*4, j*4+4) and [64+j*4, 64+j*4+4)
        const float* srow = src + (size_t)self * D;
        f32x4 sv0 = *(const f32x4*)(srow + j * 4);
        f32x4 sv1 = *(const f32x4*)(srow + 64 + j * 4);
        f32x4 s0 = (f32x4){0.f,0.f,0.f,0.f};
        f32x4 s1 = (f32x4){0.f,0.f,0.f,0.f};
        #pragma unroll
        for (int k = 0; k < K_NEI; ++k) {
            const float* r = src + (size_t)idx[k] * D;
            s0 += *(const f32x4*)(r + j * 4);
            s1 += *(const f32x4*)(r + 64 + j * 4);
        }
        *(uint2*)(c + j * 4)       = cvt4(sv0);
        *(uint2*)(c + 64 + j * 4)  = cvt4(sv1);
        *(uint2*)(c + 128 + j * 4) = cvt4(s0 * 0.1f);
        *(uint2*)(c + 192 + j * 4) = cvt4(s1 * 0.1f);
    } else {
        const uint16_t* src = (const uint16_t*)src_;
        // lane j covers cols [j*8, j*8+8) of the 128-wide bf16 source
        uint4 sv = *(const uint4*)(src + (size_t)self * D + j * 8);
        float s0=0,s1=0,s2=0,s3=0,s4=0,s5=0,s6=0,s7=0;
        #pragma unroll
        for (int k = 0; k < K_NEI; ++k) {
            uint4 v = *(const uint4*)(src + (size_t)idx[k] * D + j * 8);
            s0 += bf2f(v.x & 0xFFFFu); s1 += bf2f(v.x >> 16);
            s2 += bf2f(v.y & 0xFFFFu); s3 += bf2f(v.y >> 16);
            s4 += bf2f(v.z & 0xFFFFu); s5 += bf2f(v.z >> 16);
            s6 += bf2f(v.w & 0xFFFFu); s7 += bf2f(v.w >> 16);
        }
        *(uint4*)(c + j * 8) = sv;                     // self half: raw copy
        const float inv = 0.1f;
        uint4 o;
        o.x = pack2(s0 * inv, s1 * inv); o.y = pack2(s2 * inv, s3 * inv);
        o.z = pack2(s4 * inv, s5 * inv); o.w = pack2(s6 * inv, s7 * inv);
        *(uint4*)(c + 128 + j * 8) = o;
    }
}

// ============================================================================
// gemm_k256: out[M][128] = relu(A[M][256] @ Wc^T), A,Wc bf16.
// W-stationary in registers: each wave owns a 64-col half of the output
// (4 nt x 8 ks fragments = 128 VGPR), loaded straight from the native
// [128][256] layout. No LDS, no barriers. NOTE: plain __launch_bounds__(256)
// (the R1 (256,2) capped VGPR at 128 and forced W re-materialization).
// Swapped operands: mfma(Wfrag, Afrag) -> lane owns 1 node-row x 4
// consecutive out-cols per fragment -> 8 B bf16 / 16 B f32 stores.
// ============================================================================
template <bool OUT_F32>
__global__ __launch_bounds__(256)
void gemm_k256(const uint16_t* __restrict__ A,    // [M][256] bf16
               const uint16_t* __restrict__ Wc,   // [128][256] bf16
               void* __restrict__ out_, int M)
{
    const int tid  = threadIdx.x;
    const int wave = tid >> 6;
    const int lane = tid & 63;
    const int r16  = lane & 15;
    const int q    = lane >> 4;
    const int h    = wave & 1;                     // 64-col half of output

    const int nTiles = M >> 4;
    const int stride = gridDim.x * 2;              // 2 waves per tile
    int tile = blockIdx.x * 2 + (wave >> 1);
    if (tile >= nTiles) return;

    // W fragments: out-col m = h*64 + nt*16 + r16, k = ks*32 + q*8 + 0..7
    bf16x8 Wf[4][8];
    {
        const uint16_t* wb = Wc + (size_t)(h * 64 + r16) * 256 + q * 8;
        #pragma unroll
        for (int nt = 0; nt < 4; ++nt)
            #pragma unroll
            for (int ks = 0; ks < 8; ++ks)
                Wf[nt][ks] = *(const bf16x8*)(wb + nt * 16 * 256 + ks * 32);
    }

    uint4 preB[8];
    {
        const uint16_t* row = A + (size_t)(tile * 16 + r16) * 256 + q * 8;
        #pragma unroll
        for (int ks = 0; ks < 8; ++ks) preB[ks] = *(const uint4*)(row + ks * 32);
    }

    while (tile < nTiles) {
        const int nxt = tile + stride;

        bf16x8 a[8];
        #pragma unroll
        for (int ks = 0; ks < 8; ++ks) a[ks] = u4_as_bf16x8(preB[ks]);

        if (nxt < nTiles) {
            const uint16_t* row = A + (size_t)(nxt * 16 + r16) * 256 + q * 8;
            #pragma unroll
            for (int ks = 0; ks < 8; ++ks) preB[ks] = *(const uint4*)(row + ks * 32);
        }

        f32x4 acc[4];
        #pragma unroll
        for (int nt = 0; nt < 4; ++nt) acc[nt] = (f32x4){0.f,0.f,0.f,0.f};

        #pragma unroll
        for (int ks = 0; ks < 8; ++ks)
            #pragma unroll
            for (int nt = 0; nt < 4; ++nt)
                acc[nt] = __builtin_amdgcn_mfma_f32_16x16x32_bf16(Wf[nt][ks], a[ks], acc[nt], 0, 0, 0);

        // lane owns row tile*16+r16, cols h*64 + nt*16 + q*4 .. +3
        const size_t row = (size_t)(tile * 16 + r16);
        const int col0 = h * 64 + q * 4;
        #pragma unroll
        for (int nt = 0; nt < 4; ++nt) {
            f32x4 v = acc[nt];
            v[0] = v[0] > 0.f ? v[0] : 0.f;
            v[1] = v[1] > 0.f ? v[1] : 0.f;
            v[2] = v[2] > 0.f ? v[2] : 0.f;
            v[3] = v[3] > 0.f ? v[3] : 0.f;
            if (OUT_F32)
                *(f32x4*)((float*)out_ + row * 128 + col0 + nt * 16) = v;
            else
                *(uint2*)((uint16_t*)out_ + row * 128 + col0 + nt * 16) = cvt4(v);
        }
        tile = nxt;
    }
}

// ============================================================================
// Fallback: R3 fused kernel (proven) — only if ws too small for path A.
// ============================================================================
template <bool FEATS_F32, bool OUT_F32>
__global__ void sage_layer(const void* __restrict__ feats_,
                           const float* __restrict__ W,
                           const int* __restrict__ self_idx,
                           const int* __restrict__ neigh_idx,
                           void* __restrict__ out_)
{
    __shared__ __align__(16) uint16_t Alds[TILE_M * 128];
    __shared__ __align__(16) uint16_t Wlds[128 * 128];

    const int tid  = threadIdx.x;
    const int wave = tid >> 6;
    const int lane = tid & 63;
    const int r16  = lane & 15;
    const int q    = lane >> 4;
    const int G    = blockIdx.x * TILE_M;

    const float*    feats_f = (const float*)feats_;
    const uint16_t* feats_b = (const uint16_t*)feats_;

    f32x4 acc[8];
    #pragma unroll
    for (int nt = 0; nt < 8; ++nt) acc[nt] = (f32x4){0.f, 0.f, 0.f, 0.f};

    for (int half = 0; half < 2; ++half) {
        #pragma unroll
        for (int it = 0; it < 8; ++it) {
            int t = it * 256 + tid;
            int j = t >> 4, c = t & 15;
            const float* src = W + (size_t)j * 256 + half * 128 + c * 8;
            f32x4 w0 = *(const f32x4*)(src);
            f32x4 w1 = *(const f32x4*)(src + 4);
            uint4 o;
            o.x = pack2(w0[0], w0[1]); o.y = pack2(w0[2], w0[3]);
            o.z = pack2(w1[0], w1[1]); o.w = pack2(w1[2], w1[3]);
            int cs = c ^ (j & 15);
            *(uint4*)(Wlds + j * 128 + cs * 8) = o;
        }
        if (half == 0) {
            #pragma unroll
            for (int it = 0; it < 4; ++it) {
                int t = it * 256 + tid;
                int n = t >> 4, c = t & 15;
                int node = self_idx[G + n];
                uint4 o;
                if (FEATS_F32) {
                    const float* src = feats_f + (size_t)node * D + c * 8;
                    f32x4 f0 = *(const f32x4*)(src);
                    f32x4 f1 = *(const f32x4*)(src + 4);
                    o.x = pack2(f0[0], f0[1]); o.y = pack2(f0[2], f0[3]);
                    o.z = pack2(f1[0], f1[1]); o.w = pack2(f1[2], f1[3]);
                } else {
                    o = *(const uint4*)(feats_b + (size_t)node * D + c * 8);
                }
                int cs = c ^ (n & 15);
                *(uint4*)(Alds + n * 128 + cs * 8) = o;
            }
        } else {
            #pragma unroll
            for (int it = 0; it < 4; ++it) {
                int t = it * 256 + tid;
                int n = t >> 4, c = t & 15;
                const int* nrow = neigh_idx + (size_t)(G + n) * K_NEI;
                float s0=0,s1=0,s2=0,s3=0,s4=0,s5=0,s6=0,s7=0;
                #pragma unroll
                for (int k = 0; k < K_NEI; ++k) {
                    if (FEATS_F32) {
                        const float* src = feats_f + (size_t)nrow[k] * D + c * 8;
                        f32x4 f0 = *(const f32x4*)(src);
                        f32x4 f1 = *(const f32x4*)(src + 4);
                        s0 += f0[0]; s1 += f0[1]; s2 += f0[2]; s3 += f0[3];
                        s4 += f1[0]; s5 += f1[1]; s6 += f1[2]; s7 += f1[3];
                    } else {
                        uint4 v = *(const uint4*)(feats_b + (size_t)nrow[k] * D + c * 8);
                        s0 += bf2f(v.x & 0xFFFFu); s1 += bf2f(v.x >> 16);
                        s2 += bf2f(v.y & 0xFFFFu); s3 += bf2f(v.y >> 16);
                        s4 += bf2f(v.z & 0xFFFFu); s5 += bf2f(v.z >> 16);
                        s6 += bf2f(v.w & 0xFFFFu); s7 += bf2f(v.w >> 16);
                    }
                }
                const float inv = 0.1f;
                uint4 o;
                o.x = pack2(s0 * inv, s1 * inv);
                o.y = pack2(s2 * inv, s3 * inv);
                o.z = pack2(s4 * inv, s5 * inv);
                o.w = pack2(s6 * inv, s7 * inv);
                int cs = c ^ (n & 15);
                *(uint4*)(Alds + n * 128 + cs * 8) = o;
            }
        }
        __syncthreads();

        #pragma unroll
        for (int ks = 0; ks < 4; ++ks) {
            int cidx = ks * 4 + q;
            bf16x8 a = *(const bf16x8*)(Alds + (wave * 16 + r16) * 128 + ((cidx ^ r16) * 8));
            bf16x8 b[8];
            #pragma unroll
            for (int nt = 0; nt < 8; ++nt) {
                int jj = nt * 16 + r16;
                b[nt] = *(const bf16x8*)(Wlds + jj * 128 + ((cidx ^ r16) * 8));
            }
            #pragma unroll
            for (int nt = 0; nt < 8; ++nt)
                acc[nt] = __builtin_amdgcn_mfma_f32_16x16x32_bf16(a, b[nt], acc[nt], 0, 0, 0);
        }
        __syncthreads();
    }

    const int row_base = G + wave * 16 + q * 4;
    #pragma unroll
    for (int nt = 0; nt < 8; ++nt) {
        int col = nt * 16 + r16;
        #pragma unroll
        for (int r = 0; r < 4; ++r) {
            float v = acc[nt][r];
            v = v > 0.f ? v : 0.f;
            if (OUT_F32) ((float*)out_)[(size_t)(row_base + r) * D + col] = v;
            else ((uint16_t*)out_)[(size_t)(row_base + r) * D + col] = (uint16_t)f2bf(v);
        }
    }
}

extern "C" void kernel_launch(void* const* d_in, const int* in_sizes, int n_in,
                              void* d_out, int out_size, void* d_ws, size_t ws_size,
                              hipStream_t stream) {
    const float* raw = (const float*)d_in[0];          // [200000][128] fp32
    const float* W1  = (const float*)d_in[1];          // [128][256] fp32
    const float* W2  = (const float*)d_in[2];          // [128][256] fp32
    const int* layer1_nodes = (const int*)d_in[3];     // [81920]
    const int* neigh0       = (const int*)d_in[4];     // [81920][10]
    const int* map_batch    = (const int*)d_in[5];     // [8192]
    const int* neigh1       = (const int*)d_in[6];     // [8192][10]

    const int N1 = in_sizes[3];            // 81920
    const int B  = in_sizes[5];            // 8192

    const size_t szC1 = (size_t)N1 * 256 * 2;          // 41.9 MB
    const size_t szH1 = (size_t)N1 * 128 * 2;          // 21.0 MB
    const size_t szC2 = (size_t)B * 256 * 2;           //  4.2 MB
    const size_t szW  = 128 * 256 * 2;                 // 64 KB
    const size_t need = szC1 + szH1 + szC2 + 2 * szW;

    if (ws_size >= need && (N1 % 16) == 0 && (B % 16) == 0) {
        uint16_t* C1  = (uint16_t*)d_ws;
        uint16_t* h1  = C1 + (size_t)N1 * 256;
        uint16_t* C2  = h1 + (size_t)N1 * 128;
        uint16_t* W1c = C2 + (size_t)B * 256;
        uint16_t* W2c = W1c + 128 * 256;

        convert_Wc<<<32, 256, 0, stream>>>(W1, W2, W1c, W2c);

        // Layer 1: gather+mean in raw-feature space, then one small GEMM.
        gather_agg<true ><<<(N1 * 16 + 255) / 256, 256, 0, stream>>>(raw, layer1_nodes, neigh0, C1, N1);

        int g1 = (N1 / 16 + 1) / 2; if (g1 > 512) g1 = 512;
        gemm_k256<false><<<g1, 256, 0, stream>>>(C1, W1c, h1, N1);

        // Layer 2: same pair on the 8192-row batch.
        gather_agg<false><<<(B * 16 + 255) / 256, 256, 0, stream>>>(h1, map_batch, neigh1, C2, B);

        int g2 = (B / 16 + 1) / 2; if (g2 > 512) g2 = 512;
        gemm_k256<true ><<<g2, 256, 0, stream>>>(C2, W2c, d_out, B);
        return;
    }

    // Fallback: R3 fused path
    uint16_t* h1 = (uint16_t*)d_ws;
    sage_layer<true,  false><<<N1 / TILE_M, 256, 0, stream>>>(raw, W1, layer1_nodes, neigh0, h1);
    sage_layer<false, true ><<<B  / TILE_M, 256, 0, stream>>>(h1,  W2, map_batch,    neigh1, d_out);
}